// Round 9
// baseline (2651.267 us; speedup 1.0000x reference)
//
#include <hip/hip_runtime.h>
#include <hip/hip_bf16.h>

#define M_DIM 32768   // SEQ*BATCH
#define N_DIM 4096
#define K_DIM 1024

// ---- 256x256 tile, BK=32, 8 waves (2Mx4N), 512 threads, 2-buffer LDS ----
// 64 KiB LDS -> 2 blocks/CU (4 waves/SIMD): prologue/epilogue of one block
// overlaps compute of the other (round-8's 1-block/CU was the limiter).
#define BM 256
#define BN 256
#define BK 32
#define NKT (K_DIM / BK)        // 32 K-tiles
#define TROWS (M_DIM / BM)      // 128
#define TCOLS (N_DIM / BN)      // 16
#define NWG (TROWS * TCOLS)     // 2048
#define BUFB 32768              // per K-tile: A 16KB @0, B 16KB @16384

typedef __attribute__((ext_vector_type(4))) float f32x4;
typedef __attribute__((ext_vector_type(8))) short bf16x8;

__device__ __forceinline__ unsigned short f2bf(float f) {
    unsigned int u = __float_as_uint(f);
    u += 0x7FFFu + ((u >> 16) & 1u);   // round-to-nearest-even
    return (unsigned short)(u >> 16);
}

__device__ __forceinline__ void gld_lds16(const void* gsrc, void* ldst) {
    __builtin_amdgcn_global_load_lds(
        (__attribute__((address_space(1))) void*)gsrc,
        (__attribute__((address_space(3))) void*)ldst,
        16, 0, 0);
}

// fp32 -> bf16 pre-cast of X and W into workspace (linear [row][k] layout).
__global__ void cast_kernel(const float* __restrict__ x, const float* __restrict__ w,
                            unsigned short* __restrict__ wsA, unsigned short* __restrict__ wsB) {
    const int nA = M_DIM * (K_DIM / 8);
    const int nB = N_DIM * (K_DIM / 8);
    const int total = nA + nB;
    const int stride = gridDim.x * blockDim.x;
    for (int i = blockIdx.x * blockDim.x + threadIdx.x; i < total; i += stride) {
        const float* src; unsigned short* dst; int g;
        if (i < nA) { src = x; dst = wsA; g = i; }
        else        { src = w; dst = wsB; g = i - nA; }
        const f32x4* s4 = (const f32x4*)(src + (size_t)g * 8);
        f32x4 v0 = s4[0];
        f32x4 v1 = s4[1];
        bf16x8 o;
        o[0] = (short)f2bf(v0[0]); o[1] = (short)f2bf(v0[1]);
        o[2] = (short)f2bf(v0[2]); o[3] = (short)f2bf(v0[3]);
        o[4] = (short)f2bf(v1[0]); o[5] = (short)f2bf(v1[1]);
        o[6] = (short)f2bf(v1[2]); o[7] = (short)f2bf(v1[3]);
        *(bf16x8*)(dst + (size_t)g * 8) = o;
    }
}

// ---- fences / waits (rule #18: every wait/barrier followed by sched_barrier) ----
#define SCHED0() __builtin_amdgcn_sched_barrier(0)
#define CFENCE() asm volatile("" ::: "memory")
#define BARR()   do { CFENCE(); SCHED0(); __builtin_amdgcn_s_barrier(); \
                      SCHED0(); CFENCE(); } while (0)
#define LGK0()   do { asm volatile("s_waitcnt lgkmcnt(0)" ::: "memory"); SCHED0(); } while (0)
#define VM(n)    do { asm volatile("s_waitcnt vmcnt(" #n ")" ::: "memory"); SCHED0(); } while (0)

#define MFMA_(a, b, c) __builtin_amdgcn_mfma_f32_16x16x32_bf16((a), (b), (c), 0, 0, 0)

// stage one half (128 rows x 32 cols bf16 = 8KB) of A or B: 1 load/thread
#define STAGE_A(ST, H, kt) \
    gld_lds16(Abf + gA + (size_t)(H) * 128 * K_DIM + (kt) * BK, \
              smem + (ST) + (H) * 8192 + (size_t)t * 16)
#define STAGE_B(ST, H, kt) \
    gld_lds16(Bbf + gB + (size_t)(H) * 128 * K_DIM + (kt) * BK, \
              smem + (ST) + 16384 + (H) * 8192 + (size_t)t * 16)

// ds_reads: A lower frags (0-3) / A upper frags (4-7) / all 4 B frags
#define READ_A0(AR) do {                                                 \
    _Pragma("unroll")                                                    \
    for (int _mm = 0; _mm < 4; ++_mm)                                    \
        Af[_mm] = *(const bf16x8*)(smem + (AR) + _mm * 1024);            \
} while (0)
#define READ_A1(AR) do {                                                 \
    _Pragma("unroll")                                                    \
    for (int _mm = 0; _mm < 4; ++_mm)                                    \
        Af[_mm] = *(const bf16x8*)(smem + (AR) + (4 + _mm) * 1024);      \
} while (0)
#define READ_B4(BR) do {                                                 \
    _Pragma("unroll")                                                    \
    for (int _nn = 0; _nn < 4; ++_nn)                                    \
        Bf[_nn] = *(const bf16x8*)(smem + (BR) + _nn * 1024);            \
} while (0)

// one C-quadrant x K=32: 8 MFMA; Af holds the CURRENT 4 m-frags (mh half),
// Bf holds all 4 n-frags for the K-tile (read once in ph1, reused in ph2).
#define MAC(mh, nh) do {                                                 \
    __builtin_amdgcn_s_setprio(1);                                       \
    _Pragma("unroll")                                                    \
    for (int _mm = 0; _mm < 4; ++_mm)                                    \
        _Pragma("unroll")                                                \
        for (int _nn = 0; _nn < 2; ++_nn)                                \
            acc[(mh) * 4 + _mm][(nh) * 2 + _nn] =                        \
                MFMA_(Af[_mm], Bf[(nh) * 2 + _nn],                       \
                      acc[(mh) * 4 + _mm][(nh) * 2 + _nn]);              \
    __builtin_amdgcn_s_setprio(0);                                       \
} while (0)

// One K-tile k (buffer RD), 2 phases:
//  ph1: read A frags 0-3 + ALL B frags from RD; stage A(k+1) -> OT (other
//       buffer -- cannot collide with any read); lgkmcnt(0); 16 MFMA; barrier.
//  ph2: read A frags 4-7 (B reused from regs); stage B(k+2) -> RD (B-region
//       of RD was last read in ph1, barrier-closed); lgkmcnt(0); 16 MFMA;
//       VM(2) gate (retires tile k+1's A+B, leaves B(k+2) in flight); barrier.
// Liveness (verified): A(j) staged ph1(j-1), read ph1/ph2(j) -- 2-phase gap;
// B(j) staged ph2(j-2), read ph1(j) -- 2-phase gap.  Never drains to 0 (T4).
#define TILE(RD, OT, kA, kB) do {                                        \
    const int aR = (RD) + aOff;                                          \
    const int bR = (RD) + bOff;                                          \
    READ_A0(aR); READ_B4(bR);                                            \
    STAGE_A(OT, 0, kA); STAGE_A(OT, 1, kA);                              \
    LGK0(); MAC(0, 0); MAC(0, 1); BARR();                                \
    READ_A1(aR);                                                         \
    STAGE_B(RD, 0, kB); STAGE_B(RD, 1, kB);                              \
    LGK0(); MAC(1, 1); MAC(1, 0); VM(2); BARR();                         \
} while (0)

__global__ __launch_bounds__(512, 4)
void gemm_kernel(const unsigned short* __restrict__ Abf,
                 const unsigned short* __restrict__ Bbf,
                 const float* __restrict__ bias, float* __restrict__ C) {
    __shared__ unsigned char smem[2 * BUFB];   // 64 KiB -> 2 blocks/CU

    const int t    = threadIdx.x;               // 0..511
    const int lane = t & 63;
    const int wave = t >> 6;
    const int wr   = wave >> 2;                 // 0..1 (M half)
    const int wc   = wave & 3;                  // 0..3 (N quarter)

    // XCD-aware mapping, per-XCD row-major (A-panel reused 16x in L2)
    const int bid  = blockIdx.x;
    const int xcd  = bid & 7;
    const int jj   = bid >> 3;                  // 0..255
    const int row0 = (xcd * 16 + (jj >> 4)) * BM;
    const int col0 = (jj & 15) * BN;

    // ---- staging source (pre-swizzled global): LDS slot within a half:
    // row = t>>2, s = t&3; content k8-group = s ^ ((row>>1)&3). ----
    const int srow = t >> 2;                    // 0..127
    const int jsrc = (t & 3) ^ ((t >> 3) & 3);
    const size_t gA = (size_t)(row0 + srow) * K_DIM + jsrc * 8;
    const size_t gB = (size_t)(col0 + srow) * K_DIM + jsrc * 8;

    // ---- ds_read bases ((row>>1)&3 == (laneR>>1)&3 for all fragment rows) ----
    const int laneR = lane & 15;
    const int jb    = lane >> 4;                // k8-group 0..3
    const int slotR = (jb ^ ((laneR >> 1) & 3)) * 16;
    const int aOff  = wr * 8192 + laneR * 64 + slotR;
    const int bOff  = 16384 + wc * 4096 + laneR * 64 + slotR;

    f32x4  acc[8][4] = {};
    bf16x8 Af[4];   // current A m-half fragments (ph1: 0-3, ph2: 4-7)
    bf16x8 Bf[4];   // ALL 4 B n-frags of the current K-tile (read in ph1)

    // ---- prologue: A(0),B(0) -> buf0; B(1) -> buf1 (6 loads) ----
    STAGE_A(0, 0, 0); STAGE_A(0, 1, 0); STAGE_B(0, 0, 0); STAGE_B(0, 1, 0);
    STAGE_B(BUFB, 0, 1); STAGE_B(BUFB, 1, 1);
    VM(2);      // retire A(0),B(0); B(1) stays in flight
    BARR();

    // ---- main loop: tiles 0..29, two per iteration (buf0 / buf1) ----
    for (int it = 0; it < 15; ++it) {
        const int k0 = 2 * it;
        TILE(0,    BUFB, k0 + 1, k0 + 2);   // tile k0 (buf0): A(k0+1)->buf1, B(k0+2)->buf0
        TILE(BUFB, 0,    k0 + 2, k0 + 3);   // tile k0+1 (buf1): A(k0+2)->buf0, B(k0+3)->buf1
    }

    // ---- tile 30 (buf0): stage A(31)->buf1 only; full drain at end ----
    {
        const int aR = 0 + aOff, bR = 0 + bOff;
        READ_A0(aR); READ_B4(bR);
        STAGE_A(BUFB, 0, 31); STAGE_A(BUFB, 1, 31);
        LGK0(); MAC(0, 0); MAC(0, 1); BARR();
        READ_A1(aR);
        LGK0(); MAC(1, 1); MAC(1, 0); VM(0); BARR();   // retire B(31), A(31)
    }
    // ---- tile 31 (buf1): no staging, no gate ----
    {
        const int aR = BUFB + aOff, bR = BUFB + bOff;
        READ_A0(aR); READ_B4(bR);
        LGK0(); MAC(0, 0); MAC(0, 1); BARR();
        READ_A1(aR);
        LGK0(); MAC(1, 1); MAC(1, 0);
    }

    // ---- epilogue: bias after all gates; C layout col=lane&15,
    // row=(lane>>4)*4+reg ----
    const int cr = (lane >> 4) * 4;
    const int cc = lane & 15;
    float bv[4];
    #pragma unroll
    for (int n = 0; n < 4; ++n)
        bv[n] = bias[col0 + wc * 64 + n * 16 + cc];
    #pragma unroll
    for (int m = 0; m < 8; ++m) {
        const int gr = row0 + wr * 128 + m * 16 + cr;
        #pragma unroll
        for (int n = 0; n < 4; ++n) {
            const int gc = col0 + wc * 64 + n * 16 + cc;
            float* p = C + (size_t)gr * N_DIM + gc;
            p[0]                 = acc[m][n][0] + bv[n];
            p[(size_t)N_DIM]     = acc[m][n][1] + bv[n];
            p[(size_t)2 * N_DIM] = acc[m][n][2] + bv[n];
            p[(size_t)3 * N_DIM] = acc[m][n][3] + bv[n];
        }
    }
}

// Fallback (no workspace): round-2 verified 128x128 fused-cast kernel.
__global__ __launch_bounds__(256, 4)
void gemm_fallback(const float* __restrict__ Af, const float* __restrict__ Bf,
                   const float* __restrict__ bias, float* __restrict__ C) {
    __shared__ unsigned char smem[32768];
    const int t = threadIdx.x, lane = t & 63, wave = t >> 6;
    const int wr = wave >> 1, wc = wave & 1;
    const int bid = blockIdx.x;
    const int swz = (bid & 7) * ((M_DIM / 128) * (N_DIM / 128) / 8) + (bid >> 3);
    const int row0 = (swz / (N_DIM / 128)) * 128;
    const int col0 = (swz % (N_DIM / 128)) * 128;
    const int srow = t >> 3;
    const int sj   = (t & 7) ^ (srow & 7);
    const int aoff0 = (row0 + srow) * K_DIM + sj * 8;
    const int boff0 = (col0 + srow) * K_DIM + sj * 8;
    f32x4 acc[4][4] = {};
    const int laneR = lane & 15, jb = lane >> 4, lx = lane & 7;
    f32x4 ra[4][2], rb[4][2];
    for (int kt = 0; kt < K_DIM / 64; ++kt) {
        const int kofs = kt * 64;
        #pragma unroll
        for (int i = 0; i < 4; ++i) {
            const float* pa = Af + aoff0 + i * (32 * K_DIM) + kofs;
            ra[i][0] = *(const f32x4*)pa; ra[i][1] = *(const f32x4*)(pa + 4);
            const float* pb = Bf + boff0 + i * (32 * K_DIM) + kofs;
            rb[i][0] = *(const f32x4*)pb; rb[i][1] = *(const f32x4*)(pb + 4);
        }
        #pragma unroll
        for (int i = 0; i < 4; ++i) {
            bf16x8 oa, ob;
            #pragma unroll
            for (int q = 0; q < 4; ++q) {
                oa[q] = (short)f2bf(ra[i][0][q]); oa[q + 4] = (short)f2bf(ra[i][1][q]);
                ob[q] = (short)f2bf(rb[i][0][q]); ob[q + 4] = (short)f2bf(rb[i][1][q]);
            }
            *(bf16x8*)(smem + i * 4096 + t * 16) = oa;
            *(bf16x8*)(smem + 16384 + i * 4096 + t * 16) = ob;
        }
        __syncthreads();
        #pragma unroll
        for (int kk = 0; kk < 2; ++kk) {
            bf16x8 af[4], bfr[4];
            #pragma unroll
            for (int m = 0; m < 4; ++m) {
                const int r = wr * 64 + m * 16 + laneR;
                af[m] = *(const bf16x8*)(smem + r * 128 + (((kk * 4 + jb) ^ lx) * 16));
            }
            #pragma unroll
            for (int n = 0; n < 4; ++n) {
                const int r = wc * 64 + n * 16 + laneR;
                bfr[n] = *(const bf16x8*)(smem + 16384 + r * 128 + (((kk * 4 + jb) ^ lx) * 16));
            }
            #pragma unroll
            for (int m = 0; m < 4; ++m)
                #pragma unroll
                for (int n = 0; n < 4; ++n)
                    acc[m][n] = __builtin_amdgcn_mfma_f32_16x16x32_bf16(
                        af[m], bfr[n], acc[m][n], 0, 0, 0);
        }
        __syncthreads();
    }
    const int cr = (lane >> 4) * 4, cc = lane & 15;
    float bv[4];
    #pragma unroll
    for (int n = 0; n < 4; ++n) bv[n] = bias[col0 + wc * 64 + n * 16 + cc];
    #pragma unroll
    for (int m = 0; m < 4; ++m) {
        const int gr = row0 + wr * 64 + m * 16 + cr;
        #pragma unroll
        for (int n = 0; n < 4; ++n) {
            const int gc = col0 + wc * 64 + n * 16 + cc;
            float* p = C + (size_t)gr * N_DIM + gc;
            p[0]                 = acc[m][n][0] + bv[n];
            p[(size_t)N_DIM]     = acc[m][n][1] + bv[n];
            p[(size_t)2 * N_DIM] = acc[m][n][2] + bv[n];
            p[(size_t)3 * N_DIM] = acc[m][n][3] + bv[n];
        }
    }
}

extern "C" void kernel_launch(void* const* d_in, const int* in_sizes, int n_in,
                              void* d_out, int out_size, void* d_ws, size_t ws_size,
                              hipStream_t stream) {
    const float* x    = (const float*)d_in[0];
    const float* w    = (const float*)d_in[1];
    const float* bias = (const float*)d_in[2];
    float* out        = (float*)d_out;

    const size_t needA = (size_t)M_DIM * K_DIM * sizeof(unsigned short);
    const size_t needB = (size_t)N_DIM * K_DIM * sizeof(unsigned short);

    if (ws_size >= needA + needB) {
        unsigned short* wsA = (unsigned short*)d_ws;
        unsigned short* wsB = wsA + (size_t)M_DIM * K_DIM;
        cast_kernel<<<4096, 256, 0, stream>>>(x, w, wsA, wsB);
        gemm_kernel<<<NWG, 512, 0, stream>>>(wsA, wsB, bias, out);
    } else {
        gemm_fallback<<<(M_DIM / 128) * (N_DIM / 128), 256, 0, stream>>>(x, w, bias, out);
    }
}

// Round 10
// 349.826 us; speedup vs baseline: 7.5788x; 7.5788x over previous
//
#include <hip/hip_runtime.h>
#include <hip/hip_bf16.h>

#define M_DIM 32768   // SEQ*BATCH
#define N_DIM 4096
#define K_DIM 1024

// ---- 256x256 tile, BK=64, 8 waves (2Mx4N), 512 threads, 2-buffer LDS ----
#define BM 256
#define BN 256
#define BK 64
#define NKT (K_DIM / BK)        // 16 K-tiles (windows)
#define TROWS (M_DIM / BM)      // 128
#define TCOLS (N_DIM / BN)      // 16
#define NWG (TROWS * TCOLS)     // 2048
#define BUFB 65536              // per buffer: A 32KB @0, B 32KB @32768

typedef __attribute__((ext_vector_type(4))) float f32x4;
typedef __attribute__((ext_vector_type(8))) short bf16x8;

__device__ __forceinline__ unsigned short f2bf(float f) {
    unsigned int u = __float_as_uint(f);
    u += 0x7FFFu + ((u >> 16) & 1u);   // round-to-nearest-even
    return (unsigned short)(u >> 16);
}

__device__ __forceinline__ void gld_lds16(const void* gsrc, void* ldst) {
    __builtin_amdgcn_global_load_lds(
        (__attribute__((address_space(1))) void*)gsrc,
        (__attribute__((address_space(3))) void*)ldst,
        16, 0, 0);
}

// fp32 -> bf16 pre-cast of X and W into workspace (linear [row][k] layout).
__global__ void cast_kernel(const float* __restrict__ x, const float* __restrict__ w,
                            unsigned short* __restrict__ wsA, unsigned short* __restrict__ wsB) {
    const int nA = M_DIM * (K_DIM / 8);
    const int nB = N_DIM * (K_DIM / 8);
    const int total = nA + nB;
    const int stride = gridDim.x * blockDim.x;
    for (int i = blockIdx.x * blockDim.x + threadIdx.x; i < total; i += stride) {
        const float* src; unsigned short* dst; int g;
        if (i < nA) { src = x; dst = wsA; g = i; }
        else        { src = w; dst = wsB; g = i - nA; }
        const f32x4* s4 = (const f32x4*)(src + (size_t)g * 8);
        f32x4 v0 = s4[0];
        f32x4 v1 = s4[1];
        bf16x8 o;
        o[0] = (short)f2bf(v0[0]); o[1] = (short)f2bf(v0[1]);
        o[2] = (short)f2bf(v0[2]); o[3] = (short)f2bf(v0[3]);
        o[4] = (short)f2bf(v1[0]); o[5] = (short)f2bf(v1[1]);
        o[6] = (short)f2bf(v1[2]); o[7] = (short)f2bf(v1[3]);
        *(bf16x8*)(dst + (size_t)g * 8) = o;
    }
}

// ---- fences / waits (rule #18: every wait/barrier followed by sched_barrier) ----
#define SCHED0() __builtin_amdgcn_sched_barrier(0)
#define CFENCE() asm volatile("" ::: "memory")
#define BARR()   do { CFENCE(); SCHED0(); __builtin_amdgcn_s_barrier(); \
                      SCHED0(); CFENCE(); } while (0)
#define LGK0()   do { asm volatile("s_waitcnt lgkmcnt(0)" ::: "memory"); SCHED0(); } while (0)
#define VM(n)    do { asm volatile("s_waitcnt vmcnt(" #n ")" ::: "memory"); SCHED0(); } while (0)

#define MFMA_(a, b, c) __builtin_amdgcn_mfma_f32_16x16x32_bf16((a), (b), (c), 0, 0, 0)

// stage one half (128 rows x 64 cols bf16 = 16KB) of A or B: 2 loads/thread
#define STAGE_A(BB, H, kt) do {                                                  \
    const unsigned short* _s = Abf + gA + (size_t)(H) * 128 * K_DIM + (kt) * BK; \
    unsigned char* _d = smem + (BB) + (H) * 16384 + (size_t)t * 16;              \
    gld_lds16(_s, _d);                                                           \
    gld_lds16(_s + 64 * K_DIM, _d + 8192);                                       \
} while (0)

#define STAGE_B(BB, H, kt) do {                                                  \
    const unsigned short* _s = Bbf + gB + (size_t)(H) * 128 * K_DIM + (kt) * BK; \
    unsigned char* _d = smem + (BB) + 32768 + (H) * 16384 + (size_t)t * 16;      \
    gld_lds16(_s, _d);                                                           \
    gld_lds16(_s + 64 * K_DIM, _d + 8192);                                       \
} while (0)

// ds_reads.  A frags 0-3 (mh0) / 4-7 (mh1) x 2 kk into Af (reused mh0->mh1);
// B frags 0-1 (nh0) / 2-3 (nh1) x 2 kk into Bf (ALL 4 stay live the window --
// no ph4 LDS re-read, so B-half LDS regions die at ph2).
#define READ_A0(A0, A1) do {                                             \
    _Pragma("unroll")                                                    \
    for (int _mm = 0; _mm < 4; ++_mm) {                                  \
        Af[_mm][0] = *(const bf16x8*)(smem + (A0) + _mm * 2048);         \
        Af[_mm][1] = *(const bf16x8*)(smem + (A1) + _mm * 2048);         \
    }                                                                    \
} while (0)
#define READ_A1(A0, A1) do {                                             \
    _Pragma("unroll")                                                    \
    for (int _mm = 0; _mm < 4; ++_mm) {                                  \
        Af[_mm][0] = *(const bf16x8*)(smem + (A0) + (4 + _mm) * 2048);   \
        Af[_mm][1] = *(const bf16x8*)(smem + (A1) + (4 + _mm) * 2048);   \
    }                                                                    \
} while (0)
#define READ_B0(B0, B1) do {                                             \
    _Pragma("unroll")                                                    \
    for (int _nn = 0; _nn < 2; ++_nn) {                                  \
        Bf[_nn][0] = *(const bf16x8*)(smem + (B0) + _nn * 2048);         \
        Bf[_nn][1] = *(const bf16x8*)(smem + (B1) + _nn * 2048);         \
    }                                                                    \
} while (0)
#define READ_B1(B0, B1) do {                                             \
    _Pragma("unroll")                                                    \
    for (int _nn = 0; _nn < 2; ++_nn) {                                  \
        Bf[2 + _nn][0] = *(const bf16x8*)(smem + (B0) + (2 + _nn) * 2048); \
        Bf[2 + _nn][1] = *(const bf16x8*)(smem + (B1) + (2 + _nn) * 2048); \
    }                                                                    \
} while (0)

// one C-quadrant x K=64: 16 MFMA (4m x 2n x 2kk)
#define MAC(mh, nh) do {                                                 \
    __builtin_amdgcn_s_setprio(1);                                       \
    _Pragma("unroll")                                                    \
    for (int _mm = 0; _mm < 4; ++_mm)                                    \
        _Pragma("unroll")                                                \
        for (int _nn = 0; _nn < 2; ++_nn) {                              \
            acc[(mh) * 4 + _mm][(nh) * 2 + _nn] =                        \
                MFMA_(Af[_mm][0], Bf[(nh) * 2 + _nn][0],                 \
                      acc[(mh) * 4 + _mm][(nh) * 2 + _nn]);              \
            acc[(mh) * 4 + _mm][(nh) * 2 + _nn] =                        \
                MFMA_(Af[_mm][1], Bf[(nh) * 2 + _nn][1],                 \
                      acc[(mh) * 4 + _mm][(nh) * 2 + _nn]);              \
        }                                                                \
    __builtin_amdgcn_s_setprio(0);                                       \
} while (0)

// One window (K-tile w in buffer RD; OT = other buffer).  4 phases.
// Region lifetimes (verified per-wave): A-halves read ph1+ph3, dead after
// ph3; B-halves read ph1+ph2, dead after ph2.  Stage slots:
//   ph1: tile w+1 B-half1 -> OT  (OT.B1 died ph2 of window w-1)
//   ph2: tile w+1 A-half1 -> OT  (OT.A1 died ph3 of window w-1)
//   ph3: tile w+2 B-half0 -> RD  (RD.B0 died ph2 of THIS window)
//   ph4: tile w+2 A-half0 -> RD  (RD.A0 died ph3 of THIS window)
// Gate VM(4) at ph4: outstanding 6 halves (12 loads) -> retires 8 loads =
// exactly tile w+1's 4 halves (staged ph3,4(w-1) + ph1,2(w)); leaves tile
// w+2's 2 halves in flight.  Never drains to 0 (T4).
#define WINDOW(RD, OT, KA, KB) do {                                      \
    const int a0 = (RD) + aOff0, a1 = (RD) + aOff1;                      \
    const int b0 = (RD) + bOff0, b1 = (RD) + bOff1;                      \
    READ_A0(a0, a1); READ_B0(b0, b1); STAGE_B(OT, 1, KA);                \
    BARR(); LGK0(); MAC(0, 0); BARR();                                   \
    READ_B1(b0, b1);                 STAGE_A(OT, 1, KA);                 \
    BARR(); LGK0(); MAC(0, 1); BARR();                                   \
    READ_A1(a0, a1);                 STAGE_B(RD, 0, KB);                 \
    BARR(); LGK0(); MAC(1, 1); BARR();                                   \
    STAGE_A(RD, 0, KB);                                                  \
    MAC(1, 0); VM(4); BARR();                                            \
} while (0)

__global__ __launch_bounds__(512, 2)
void gemm_kernel(const unsigned short* __restrict__ Abf,
                 const unsigned short* __restrict__ Bbf,
                 const float* __restrict__ bias, float* __restrict__ C) {
    __shared__ unsigned char smem[2 * BUFB];   // 128 KiB

    const int t    = threadIdx.x;               // 0..511
    const int lane = t & 63;
    const int wave = t >> 6;
    const int wr   = wave >> 2;                 // 0..1 (M half)
    const int wc   = wave & 3;                  // 0..3 (N quarter)

    // XCD-aware mapping, per-XCD row-major (A-panel reused 16x in L2)
    const int bid  = blockIdx.x;
    const int xcd  = bid & 7;
    const int jj   = bid >> 3;                  // 0..255
    const int row0 = (xcd * 16 + (jj >> 4)) * BM;
    const int col0 = (jj & 15) * BN;

    // ---- staging source (pre-swizzled global: jsrc = slot ^ (row&7)) ----
    const int rbase = t >> 3;                   // 0..63
    const int jsrc  = (t & 7) ^ (rbase & 7);
    const size_t gA = (size_t)(row0 + rbase) * K_DIM + jsrc * 8;
    const size_t gB = (size_t)(col0 + rbase) * K_DIM + jsrc * 8;

    // ---- ds_read bases (swizzle re-applied on read; r&7 == lane&7 for all
    // fragment rows since m*16, wr*128, n*16, wc*64 are multiples of 8) ----
    const int laneR = lane & 15;
    const int jb    = lane >> 4;                // k8-group 0..3
    const int lx7   = lane & 7;
    const int slotA = (jb ^ lx7) * 16;
    const int aOff0 = (wr * 128 + laneR) * 128 + slotA;   // kk=0
    const int aOff1 = aOff0 ^ 64;                         // kk=1
    const int bOff0 = 32768 + (wc * 64 + laneR) * 128 + slotA;
    const int bOff1 = bOff0 ^ 64;

    f32x4  acc[8][4] = {};
    bf16x8 Af[4][2];    // current A m-half (mh0 overwritten by mh1 at ph3)
    bf16x8 Bf[4][2];    // ALL 4 B n-frags x 2 kk, live through the window

    // ---- prologue: tile0 all 4 halves -> buf0; tile1 H0 halves -> buf1 ----
    STAGE_B(0, 0, 0); STAGE_A(0, 0, 0); STAGE_B(0, 1, 0); STAGE_A(0, 1, 0);
    STAGE_B(BUFB, 0, 1); STAGE_A(BUFB, 0, 1);
    VM(4);      // retire tile0's 4 halves; tile1's H0 pair stays in flight
    BARR();

    // ---- main loop: windows 0..13 ----
    for (int it = 0; it < 7; ++it) {
        const int w = 2 * it;
        WINDOW(0,    BUFB, w + 1, w + 2);
        WINDOW(BUFB, 0,    w + 2, w + 3);
    }

    // ---- window 14 (buf0): stage tile15 H1 only; full drain at gate ----
    {
        const int a0 = 0 + aOff0, a1 = 0 + aOff1;
        const int b0 = 0 + bOff0, b1 = 0 + bOff1;
        READ_A0(a0, a1); READ_B0(b0, b1); STAGE_B(BUFB, 1, 15);
        BARR(); LGK0(); MAC(0, 0); BARR();
        READ_B1(b0, b1);                 STAGE_A(BUFB, 1, 15);
        BARR(); LGK0(); MAC(0, 1); BARR();
        READ_A1(a0, a1);
        BARR(); LGK0(); MAC(1, 1); BARR();
        MAC(1, 0); VM(0); BARR();       // retire all of tile15
    }
    // ---- window 15 (buf1): reads only, no barriers needed ----
    {
        const int a0 = BUFB + aOff0, a1 = BUFB + aOff1;
        const int b0 = BUFB + bOff0, b1 = BUFB + bOff1;
        READ_A0(a0, a1); READ_B0(b0, b1); LGK0(); MAC(0, 0);
        READ_B1(b0, b1);                  LGK0(); MAC(0, 1);
        READ_A1(a0, a1);                  LGK0(); MAC(1, 1);
        MAC(1, 0);
    }

    // ---- epilogue: bias after all gates; C layout col=lane&15,
    // row=(lane>>4)*4+reg ----
    const int cr = (lane >> 4) * 4;
    const int cc = lane & 15;
    float bv[4];
    #pragma unroll
    for (int n = 0; n < 4; ++n)
        bv[n] = bias[col0 + wc * 64 + n * 16 + cc];
    #pragma unroll
    for (int m = 0; m < 8; ++m) {
        const int gr = row0 + wr * 128 + m * 16 + cr;
        #pragma unroll
        for (int n = 0; n < 4; ++n) {
            const int gc = col0 + wc * 64 + n * 16 + cc;
            float* p = C + (size_t)gr * N_DIM + gc;
            p[0]                 = acc[m][n][0] + bv[n];
            p[(size_t)N_DIM]     = acc[m][n][1] + bv[n];
            p[(size_t)2 * N_DIM] = acc[m][n][2] + bv[n];
            p[(size_t)3 * N_DIM] = acc[m][n][3] + bv[n];
        }
    }
}

// Fallback (no workspace): round-2 verified 128x128 fused-cast kernel.
__global__ __launch_bounds__(256, 4)
void gemm_fallback(const float* __restrict__ Af, const float* __restrict__ Bf,
                   const float* __restrict__ bias, float* __restrict__ C) {
    __shared__ unsigned char smem[32768];
    const int t = threadIdx.x, lane = t & 63, wave = t >> 6;
    const int wr = wave >> 1, wc = wave & 1;
    const int bid = blockIdx.x;
    const int swz = (bid & 7) * ((M_DIM / 128) * (N_DIM / 128) / 8) + (bid >> 3);
    const int row0 = (swz / (N_DIM / 128)) * 128;
    const int col0 = (swz % (N_DIM / 128)) * 128;
    const int srow = t >> 3;
    const int sj   = (t & 7) ^ (srow & 7);
    const int aoff0 = (row0 + srow) * K_DIM + sj * 8;
    const int boff0 = (col0 + srow) * K_DIM + sj * 8;
    f32x4 acc[4][4] = {};
    const int laneR = lane & 15, jb = lane >> 4, lx = lane & 7;
    f32x4 ra[4][2], rb[4][2];
    for (int kt = 0; kt < K_DIM / 64; ++kt) {
        const int kofs = kt * 64;
        #pragma unroll
        for (int i = 0; i < 4; ++i) {
            const float* pa = Af + aoff0 + i * (32 * K_DIM) + kofs;
            ra[i][0] = *(const f32x4*)pa; ra[i][1] = *(const f32x4*)(pa + 4);
            const float* pb = Bf + boff0 + i * (32 * K_DIM) + kofs;
            rb[i][0] = *(const f32x4*)pb; rb[i][1] = *(const f32x4*)(pb + 4);
        }
        #pragma unroll
        for (int i = 0; i < 4; ++i) {
            bf16x8 oa, ob;
            #pragma unroll
            for (int q = 0; q < 4; ++q) {
                oa[q] = (short)f2bf(ra[i][0][q]); oa[q + 4] = (short)f2bf(ra[i][1][q]);
                ob[q] = (short)f2bf(rb[i][0][q]); ob[q + 4] = (short)f2bf(rb[i][1][q]);
            }
            *(bf16x8*)(smem + i * 4096 + t * 16) = oa;
            *(bf16x8*)(smem + 16384 + i * 4096 + t * 16) = ob;
        }
        __syncthreads();
        #pragma unroll
        for (int kk = 0; kk < 2; ++kk) {
            bf16x8 af[4], bfr[4];
            #pragma unroll
            for (int m = 0; m < 4; ++m) {
                const int r = wr * 64 + m * 16 + laneR;
                af[m] = *(const bf16x8*)(smem + r * 128 + (((kk * 4 + jb) ^ lx) * 16));
            }
            #pragma unroll
            for (int n = 0; n < 4; ++n) {
                const int r = wc * 64 + n * 16 + laneR;
                bfr[n] = *(const bf16x8*)(smem + 16384 + r * 128 + (((kk * 4 + jb) ^ lx) * 16));
            }
            #pragma unroll
            for (int m = 0; m < 4; ++m)
                #pragma unroll
                for (int n = 0; n < 4; ++n)
                    acc[m][n] = __builtin_amdgcn_mfma_f32_16x16x32_bf16(
                        af[m], bfr[n], acc[m][n], 0, 0, 0);
        }
        __syncthreads();
    }
    const int cr = (lane >> 4) * 4, cc = lane & 15;
    float bv[4];
    #pragma unroll
    for (int n = 0; n < 4; ++n) bv[n] = bias[col0 + wc * 64 + n * 16 + cc];
    #pragma unroll
    for (int m = 0; m < 4; ++m) {
        const int gr = row0 + wr * 64 + m * 16 + cr;
        #pragma unroll
        for (int n = 0; n < 4; ++n) {
            const int gc = col0 + wc * 64 + n * 16 + cc;
            float* p = C + (size_t)gr * N_DIM + gc;
            p[0]                 = acc[m][n][0] + bv[n];
            p[(size_t)N_DIM]     = acc[m][n][1] + bv[n];
            p[(size_t)2 * N_DIM] = acc[m][n][2] + bv[n];
            p[(size_t)3 * N_DIM] = acc[m][n][3] + bv[n];
        }
    }
}

extern "C" void kernel_launch(void* const* d_in, const int* in_sizes, int n_in,
                              void* d_out, int out_size, void* d_ws, size_t ws_size,
                              hipStream_t stream) {
    const float* x    = (const float*)d_in[0];
    const float* w    = (const float*)d_in[1];
    const float* bias = (const float*)d_in[2];
    float* out        = (float*)d_out;

    const size_t needA = (size_t)M_DIM * K_DIM * sizeof(unsigned short);
    const size_t needB = (size_t)N_DIM * K_DIM * sizeof(unsigned short);

    if (ws_size >= needA + needB) {
        unsigned short* wsA = (unsigned short*)d_ws;
        unsigned short* wsB = wsA + (size_t)M_DIM * K_DIM;
        cast_kernel<<<4096, 256, 0, stream>>>(x, w, wsA, wsB);
        gemm_kernel<<<NWG, 512, 0, stream>>>(wsA, wsB, bias, out);
    } else {
        gemm_fallback<<<(M_DIM / 128) * (N_DIM / 128), 256, 0, stream>>>(x, w, bias, out);
    }
}